// Round 1
// 58.143 us; speedup vs baseline: 1.0261x; 1.0261x over previous
//
#include <hip/hip_runtime.h>
#include <cmath>

#define SEQ 4096
#define NB 16
#define NT 1024

// ---- DPP helpers: full-wave reduce via row_shr:1,2,4,8 + row_bcast:15,31 ----
// update_dpp(old=0, src, ctrl, row_mask=0xf, bank_mask=0xf, bound_ctrl=false):
// invalid source lanes yield 0, which is the identity for add / max-of-positive,
// and (0, idx) never wins an argmax against values > 0.
template <int C>
__device__ __forceinline__ float dppf(float x) {
  return __builtin_bit_cast(
      float, __builtin_amdgcn_update_dpp(0, __builtin_bit_cast(int, x), C, 0xf, 0xf, false));
}
template <int C>
__device__ __forceinline__ int dppi(int x) {
  return __builtin_amdgcn_update_dpp(0, x, C, 0xf, 0xf, false);
}
__device__ __forceinline__ float rdlane(float x, int l) {
  return __builtin_bit_cast(float, __builtin_amdgcn_readlane(__builtin_bit_cast(int, x), l));
}

#define RSHR1 0x111
#define RSHR2 0x112
#define RSHR4 0x114
#define RSHR8 0x118
#define RBC15 0x142
#define RBC31 0x143

// One block per batch row. Thread t owns elements [4t, 4t+4).
// LDS: s_ee[i] = e_e[i] (raw exp), zeros [SEQ, SEQ+32)
//      s_se[32+i] = e_s[i],        zeros [0, 32)
//      m4e[c] = max(s_ee[4c..4c+3]), zeros for c >= 1024
//      m4s[c] = max(s_se[4c..4c+3]), zeros for c < 8
__global__ __launch_bounds__(NT, 1) void ph_kernel(
    const float* __restrict__ sl_g, const float* __restrict__ el_g,
    float* __restrict__ out) {
  const int b = blockIdx.x;
  const int tid = threadIdx.x;
  const int lane = tid & 63;
  const int wv = tid >> 6;  // 16 waves

  __shared__ __align__(16) float s_ee[SEQ + 32];
  __shared__ __align__(16) float s_se[SEQ + 32];
  __shared__ float m4e[1032];
  __shared__ float m4s[1032];
  __shared__ float2 rmax[16], rsum[16];
  __shared__ float4 rarg[16];

  const int i0 = tid << 2;
  // issue HBM loads first
  float4 sv = *(const float4*)(sl_g + b * SEQ + i0);
  float4 ev = *(const float4*)(el_g + b * SEQ + i0);

  if (tid < 32) { s_ee[SEQ + tid] = 0.0f; s_se[tid] = 0.0f; }
  if (tid < 8)  { m4e[1024 + tid] = 0.0f; m4s[tid] = 0.0f; }

  // ---------- round 1: block max (DPP, one barrier) ----------
  float ms = fmaxf(fmaxf(sv.x, sv.y), fmaxf(sv.z, sv.w));
  float me = fmaxf(fmaxf(ev.x, ev.y), fmaxf(ev.z, ev.w));
  ms = fmaxf(ms, dppf<RSHR1>(ms)); me = fmaxf(me, dppf<RSHR1>(me));
  ms = fmaxf(ms, dppf<RSHR2>(ms)); me = fmaxf(me, dppf<RSHR2>(me));
  ms = fmaxf(ms, dppf<RSHR4>(ms)); me = fmaxf(me, dppf<RSHR4>(me));
  ms = fmaxf(ms, dppf<RSHR8>(ms)); me = fmaxf(me, dppf<RSHR8>(me));
  ms = fmaxf(ms, dppf<RBC15>(ms)); me = fmaxf(me, dppf<RBC15>(me));
  ms = fmaxf(ms, dppf<RBC31>(ms)); me = fmaxf(me, dppf<RBC31>(me));
  if (lane == 63) rmax[wv] = make_float2(ms, me);
  __syncthreads();

  // cross-wave max combine: lanes 0-15 side S, 16-31 side E (32+ mirror, unused)
  {
    float2 pr = rmax[lane & 15];
    float pm = (lane & 16) ? pr.y : pr.x;
    pm = fmaxf(pm, dppf<RSHR1>(pm));
    pm = fmaxf(pm, dppf<RSHR2>(pm));
    pm = fmaxf(pm, dppf<RSHR4>(pm));
    pm = fmaxf(pm, dppf<RSHR8>(pm));
    sv.x -= 0.0f;  // keep sv live
    const float max_s = rdlane(pm, 15);
    const float max_e = rdlane(pm, 31);

    // ---------- exp (raw e-values), LDS fill, sum round ----------
    float es0 = expf(sv.x - max_s), es1 = expf(sv.y - max_s),
          es2 = expf(sv.z - max_s), es3 = expf(sv.w - max_s);
    float ee0 = expf(ev.x - max_e), ee1 = expf(ev.y - max_e),
          ee2 = expf(ev.z - max_e), ee3 = expf(ev.w - max_e);
    *(float4*)&s_ee[i0] = make_float4(ee0, ee1, ee2, ee3);
    *(float4*)&s_se[32 + i0] = make_float4(es0, es1, es2, es3);
    m4e[tid] = fmaxf(fmaxf(ee0, ee1), fmaxf(ee2, ee3));
    m4s[8 + tid] = fmaxf(fmaxf(es0, es1), fmaxf(es2, es3));

    float ss = (es0 + es1) + (es2 + es3);
    float se = (ee0 + ee1) + (ee2 + ee3);
    ss += dppf<RSHR1>(ss); se += dppf<RSHR1>(se);
    ss += dppf<RSHR2>(ss); se += dppf<RSHR2>(se);
    ss += dppf<RSHR4>(ss); se += dppf<RSHR4>(se);
    ss += dppf<RSHR8>(ss); se += dppf<RSHR8>(se);
    ss += dppf<RBC15>(ss); se += dppf<RBC15>(se);
    ss += dppf<RBC31>(ss); se += dppf<RBC31>(se);
    if (lane == 63) rsum[wv] = make_float2(ss, se);
    __syncthreads();

    // cross-wave sum combine (exact: DPP injects 0 = identity)
    float2 qr = rsum[lane & 15];
    float qm = (lane & 16) ? qr.y : qr.x;
    qm += dppf<RSHR1>(qm);
    qm += dppf<RSHR2>(qm);
    qm += dppf<RSHR4>(qm);
    qm += dppf<RSHR8>(qm);
    const float inv_s = 1.0f / rdlane(qm, 15);
    const float inv_e = 1.0f / rdlane(qm, 31);

    // probs -> global EARLY: the 512 KB write drains under the window phase
    *(float4*)(out + b * SEQ + i0) =
        make_float4(es0 * inv_s, es1 * inv_s, es2 * inv_s, es3 * inv_s);
    *(float4*)(out + NB * SEQ + b * SEQ + i0) =
        make_float4(ee0 * inv_e, ee1 * inv_e, ee2 * inv_e, ee3 * inv_e);

    // ---------- banded windows (hierarchical max4, conflict-free reads) ----------
    // end-prob window for start scores: v[j] = s_ee[i0+j], j=0..33
    //   v0..v3 = own regs; v4..v27 = m4e[t+1..t+6]; v28..v31 = c7; v32,v33 = c8
    const int t = tid;
    float4 c7 = *(float4*)&s_ee[i0 + 28];
    float2 c8 = *(float2*)&s_ee[i0 + 32];
    float a1 = m4e[t + 1], a2 = m4e[t + 2], a3 = m4e[t + 3],
          a4 = m4e[t + 4], a5 = m4e[t + 5], a6 = m4e[t + 6];
    float m16 = fmaxf(fmaxf(fmaxf(a1, a2), fmaxf(a3, a4)), fmaxf(a5, a6));
    float common = fmaxf(fmaxf(ee3, m16), fmaxf(fmaxf(c7.x, c7.y), c7.z));  // v3..v30
    float w0 = fmaxf(common, fmaxf(ee0, fmaxf(ee1, ee2)));
    float w1 = fmaxf(common, fmaxf(ee1, fmaxf(ee2, c7.w)));
    float w2 = fmaxf(common, fmaxf(ee2, fmaxf(c7.w, c8.x)));
    float w3 = fmaxf(common, fmaxf(c7.w, fmaxf(c8.x, c8.y)));

    // start-prob window for end scores: u[j] = s_se[i0+j] = e_s[i0-32+j], j=0..35
    //   u2,u3 = d0; u4..u7 = d1; u8..u31 = m4s[t+2..t+7]; u32..u35 = own regs
    float2 d0 = *(float2*)&s_se[i0 + 2];
    float4 d1 = *(float4*)&s_se[i0 + 4];
    float b2 = m4s[t + 2], b3 = m4s[t + 3], b4 = m4s[t + 4],
          b5 = m4s[t + 5], b6 = m4s[t + 6], b7 = m4s[t + 7];
    float n16 = fmaxf(fmaxf(fmaxf(b2, b3), fmaxf(b4, b5)), fmaxf(b6, b7));
    float common2 = fmaxf(fmaxf(n16, es0), fmaxf(fmaxf(d1.y, d1.z), d1.w));  // u5..u32
    float x0 = fmaxf(common2, fmaxf(d0.x, fmaxf(d0.y, d1.x)));
    float x1 = fmaxf(common2, fmaxf(d0.y, fmaxf(d1.x, es1)));
    float x2 = fmaxf(common2, fmaxf(d1.x, fmaxf(es1, es2)));
    float x3 = fmaxf(common2, fmaxf(es1, fmaxf(es2, es3)));

    // scores on RAW e-values: argmax invariant under the positive 1/(Ls*Le) scale
    float sc0 = es0 * w0, sc1 = es1 * w1, sc2 = es2 * w2, sc3 = es3 * w3;
    float tc0 = ee0 * x0, tc1 = ee1 * x1, tc2 = ee2 * x2, tc3 = ee3 * x3;

    float bsv = sc0; int bsi = i0;
    if (sc1 > bsv) { bsv = sc1; bsi = i0 + 1; }
    if (sc2 > bsv) { bsv = sc2; bsi = i0 + 2; }
    if (sc3 > bsv) { bsv = sc3; bsi = i0 + 3; }
    float bev = tc0; int bei = i0;
    if (tc1 > bev) { bev = tc1; bei = i0 + 1; }
    if (tc2 > bev) { bev = tc2; bei = i0 + 2; }
    if (tc3 > bev) { bev = tc3; bei = i0 + 3; }

#define ASTEP(C)                                                       \
    {                                                                  \
      float ov = dppf<C>(bsv); int oi = dppi<C>(bsi);                  \
      if (ov > bsv || (ov == bsv && oi < bsi)) { bsv = ov; bsi = oi; } \
      float ov2 = dppf<C>(bev); int oi2 = dppi<C>(bei);                \
      if (ov2 > bev || (ov2 == bev && oi2 < bei)) { bev = ov2; bei = oi2; } \
    }
    ASTEP(RSHR1) ASTEP(RSHR2) ASTEP(RSHR4) ASTEP(RSHR8) ASTEP(RBC15) ASTEP(RBC31)
#undef ASTEP
    if (lane == 63) rarg[wv] = make_float4(bsv, (float)bsi, bev, (float)bei);
  }
  __syncthreads();

  // ---------- final: wave 0 combines 16 partials per side ----------
  if (wv == 0) {
    float4 f = rarg[lane & 15];
    float v = (lane & 16) ? f.z : f.x;
    float ix = (lane & 16) ? f.w : f.y;
#define PSTEP(C)                                              \
    {                                                         \
      float ov = dppf<C>(v); float oix = dppf<C>(ix);         \
      if (ov > v || (ov == v && oix < ix)) { v = ov; ix = oix; } \
    }
    PSTEP(RSHR1) PSTEP(RSHR2) PSTEP(RSHR4) PSTEP(RSHR8)
#undef PSTEP
    if (lane == 15) out[2 * NB * SEQ + b] = ix;        // start_pointer
    if (lane == 31) out[2 * NB * SEQ + NB + b] = ix;   // end_pointer
  }
}

extern "C" void kernel_launch(void* const* d_in, const int* in_sizes, int n_in,
                              void* d_out, int out_size, void* d_ws, size_t ws_size,
                              hipStream_t stream) {
  const float* start_logits = (const float*)d_in[0];
  const float* end_logits = (const float*)d_in[1];
  float* out = (float*)d_out;
  ph_kernel<<<NB, NT, 0, stream>>>(start_logits, end_logits, out);
}